// Round 15
// baseline (225.704 us; speedup 1.0000x reference)
//
#include <hip/hip_runtime.h>
#include <stdint.h>

namespace {

constexpr int Bb = 8, S = 4096, D = 1024, BS = 32768;
constexpr float SCALE = 0.08838834764831845f;           // (D/NUM_HEADS)^-0.5
constexpr float FEPS  = 1.1920928955078125e-07f;        // float32 eps (2^-23)
constexpr int MAXF = 4096;                              // max rescued items
constexpr int NGP = 512;                                // gemm_G_part blocks

typedef unsigned short u16;
typedef __attribute__((ext_vector_type(8))) _Float16 f16x8;
typedef __attribute__((ext_vector_type(4))) float    f32x4;

__device__ __forceinline__ u16 f2h(float f) {
  _Float16 h = (_Float16)f;
  return __builtin_bit_cast(u16, h);
}
__device__ __forceinline__ float h2f(u16 u) {
  return (float)__builtin_bit_cast(_Float16, u);
}
__device__ __forceinline__ void gload_lds16(const void* g, void* l) {
  __builtin_amdgcn_global_load_lds((const __attribute__((address_space(1))) void*)g,
                                   (__attribute__((address_space(3))) void*)l, 16, 0, 0);
}
#define VMCNT(n) asm volatile("s_waitcnt vmcnt(" #n ")" ::: "memory")

// ---------------------------------------------------------------- prep_and_gpart
// Fused launch: blocks [0,NGP) run the K-split G partial GEMM (compute-bound),
// blocks [NGP, NGP+8192) run prep_h (HBM-bound); G GEMM overlaps under prep's
// 208 MB stream.
__global__ __launch_bounds__(256) void prep_and_gpart(
    const float* __restrict__ hidden, const float* __restrict__ pos,
    u16* __restrict__ Hf, int* __restrict__ fcnt,
    const float* __restrict__ Wq, const float* __restrict__ Wk,
    float* __restrict__ Gpart) {
  __shared__ float Qs[32][132];
  __shared__ float Ks[32][132];
  const int bid = blockIdx.x;
  const int t = threadIdx.x;

  if (bid < NGP) {
    // ---- gemm_G_part branch: 128x128 tile, 8x8/thread, K-slice of 128.
    const int i0 = (bid & 7) * 128, j0 = ((bid >> 3) & 7) * 128;
    const int kz = (bid >> 6) * 128;
    const int tx = t & 15, ty = t >> 4;
    float acc[8][8] = {};
    for (int k0 = kz; k0 < kz + 128; k0 += 32) {
      #pragma unroll
      for (int q = 0; q < 4; ++q) {
        const int c = t + q * 256;
        const int row = c >> 5, c4 = (c & 31) << 2;
        *(float4*)&Qs[row][c4] = *(const float4*)&Wq[(size_t)(k0 + row) * D + i0 + c4];
        *(float4*)&Ks[row][c4] = *(const float4*)&Wk[(size_t)(k0 + row) * D + j0 + c4];
      }
      __syncthreads();
      #pragma unroll 4
      for (int kk = 0; kk < 32; ++kk) {
        float qv[8], kv[8];
        *(float4*)&qv[0] = *(const float4*)&Qs[kk][ty << 3];
        *(float4*)&qv[4] = *(const float4*)&Qs[kk][(ty << 3) + 4];
        *(float4*)&kv[0] = *(const float4*)&Ks[kk][tx << 3];
        *(float4*)&kv[4] = *(const float4*)&Ks[kk][(tx << 3) + 4];
        #pragma unroll
        for (int a = 0; a < 8; ++a)
          #pragma unroll
          for (int b = 0; b < 8; ++b) acc[a][b] = fmaf(qv[a], kv[b], acc[a][b]);
      }
      __syncthreads();
    }
    float* gp = Gpart + (size_t)(bid >> 6) * 1048576;
    #pragma unroll
    for (int a = 0; a < 8; ++a) {
      const size_t base = (size_t)(i0 + (ty << 3) + a) * D + j0 + (tx << 3);
      *(float4*)&gp[base]     = make_float4(acc[a][0], acc[a][1], acc[a][2], acc[a][3]);
      *(float4*)&gp[base + 4] = make_float4(acc[a][4], acc[a][5], acc[a][6], acc[a][7]);
    }
    return;
  }

  // ---- prep_h branch: wave-per-row, shuffle-only reduce.
  const int pb = bid - NGP;
  if (pb == 0 && t == 0) *fcnt = 0;
  const int r = (pb << 2) + (t >> 6);                   // row in [0, BS)
  const int lane = t & 63;
  const float4* hrow = (const float4*)(hidden + (size_t)r * D);
  const float4* prow = (const float4*)(pos + (size_t)(r & (S - 1)) * D);
  float4 x[4];
  float ss = 0.f;
  #pragma unroll
  for (int i = 0; i < 4; ++i) {
    const int c = lane + (i << 6);
    const float4 hv = hrow[c];
    const float4 pv = prow[c];
    x[i].x = hv.x + pv.x; x[i].y = hv.y + pv.y;
    x[i].z = hv.z + pv.z; x[i].w = hv.w + pv.w;
    ss += x[i].x * x[i].x + x[i].y * x[i].y + x[i].z * x[i].z + x[i].w * x[i].w;
  }
  #pragma unroll
  for (int m = 1; m < 64; m <<= 1) ss += __shfl_xor(ss, m, 64);
  const float inv = 1.f / fmaxf(sqrtf(ss), 1e-12f);
  ushort4* orow = (ushort4*)(Hf + (size_t)r * D);
  #pragma unroll
  for (int i = 0; i < 4; ++i) {
    const int c = lane + (i << 6);
    orow[c] = make_ushort4(f2h(x[i].x * inv), f2h(x[i].y * inv),
                           f2h(x[i].z * inv), f2h(x[i].w * inv));
  }
}

// ---------------------------------------------------------------- gemm_G_comb
// Fixed-order sum of 8 K-slice partials -> Gf32 + Gf16.
__global__ void gemm_G_comb(const float* __restrict__ Gpart,
                            float* __restrict__ Gf32, u16* __restrict__ Gf16) {
  const size_t e = ((size_t)blockIdx.x * 256 + threadIdx.x) * 4;
  float4 a = *(const float4*)&Gpart[e];
  #pragma unroll
  for (int z = 1; z < 8; ++z) {
    const float4 p = *(const float4*)&Gpart[(size_t)z * 1048576 + e];
    a.x += p.x; a.y += p.y; a.z += p.z; a.w += p.w;
  }
  *(float4*)&Gf32[e] = a;
  *(ushort4*)&Gf16[e] = make_ushort4(f2h(a.x), f2h(a.y), f2h(a.z), f2h(a.w));
}

// ---------------------------------------------------------------- gemm_main
// FROZEN = R11-exact (96us): fp16 MFMA, 128x128 tile, BK=64, 4 waves,
// 2 blocks/CU, 0-conflict XOR swizzle, per tile: vmcnt(0); barrier;
// sched_barrier; stage(t+1); sched_barrier; compute(t).
// R14 lesson: the sched_barrier(0)s are REQUIRED (-13us without) -- they
// protect the stage-early property, preventing the compiler from sinking
// stage-issue below compute's ds_read/MFMA stream.
__global__ __launch_bounds__(256, 2) void gemm_main(
    const u16* __restrict__ Hf, const u16* __restrict__ Gf,
    float* __restrict__ adj_part) {
  __shared__ u16 Abuf[2][8192];       // 2 x 16KB (128 rows x 64 k)
  __shared__ u16 Bbuf[2][8192];       // 2 x 16KB (128 rows x 64 k)
  __shared__ float adjp[2][128];

  const int tid = threadIdx.x;
  const int bid = blockIdx.x;
  const int swz = (bid & 7) * 256 + (bid >> 3);  // XCD swizzle
  const int mt = swz >> 3, nt = swz & 7;
  const int r0 = mt << 7;             // 128-row block
  const int n0g = nt << 7;            // 128-col block

  const int wave = tid >> 6, lane = tid & 63;
  const int wr = wave >> 1;           // 0..1 -> rows wr*64
  const int wc = wave & 1;            // 0..1 -> cols wc*64
  const int frow = lane & 15;
  const int fgrp = lane >> 4;         // 0..3
  const int sw = (lane & 7) << 4;     // read-side swizzle (row&7 == lane&7)
  const int cb0 = (fgrp * 16) ^ sw;          // ks=0 frag byte col
  const int cb1 = (64 + fgrp * 16) ^ sw;     // ks=1 frag byte col
  const int Abase = (wr * 64 + frow) * 128;  // bytes
  const int Bbase = (wc * 64 + frow) * 128;  // bytes

  const int trow = tid >> 3;                 // 0..31 (row within 32-row chunk)
  const int scb = ((tid & 7) << 4) ^ ((trow & 7) << 4);  // pre-swizzled src col
  const char* Asrc = (const char*)Hf + (size_t)(r0 + trow) * 2048 + scb;
  const char* Bsrc = (const char*)Gf + (size_t)(n0g + trow) * 2048 + scb;
  const int dst16 = tid * 16;

  f32x4 acc[4][4];
  #pragma unroll
  for (int m = 0; m < 4; ++m)
    #pragma unroll
    for (int n = 0; n < 4; ++n) acc[m][n] = (f32x4){0.f, 0.f, 0.f, 0.f};

  auto stage = [&](int b, int kt) {
    #pragma unroll
    for (int q = 0; q < 4; ++q) {
      gload_lds16(Asrc + (size_t)q * 65536 + (size_t)kt * 128,
                  (char*)&Abuf[b][0] + q * 4096 + dst16);
      gload_lds16(Bsrc + (size_t)q * 65536 + (size_t)kt * 128,
                  (char*)&Bbuf[b][0] + q * 4096 + dst16);
    }
  };

  auto compute = [&](int b) {
    const char* Ab = (const char*)&Abuf[b][0];
    const char* Bp = (const char*)&Bbuf[b][0];
    #pragma unroll
    for (int ks = 0; ks < 2; ++ks) {
      const int cb = ks ? cb1 : cb0;
      f16x8 bf[4], af[4];
      #pragma unroll
      for (int n = 0; n < 4; ++n) bf[n] = *(const f16x8*)(Bp + Bbase + n * 2048 + cb);
      #pragma unroll
      for (int m = 0; m < 4; ++m) af[m] = *(const f16x8*)(Ab + Abase + m * 2048 + cb);
      __builtin_amdgcn_s_setprio(1);
      #pragma unroll
      for (int m = 0; m < 4; ++m)
        #pragma unroll
        for (int n = 0; n < 4; ++n)
          acc[m][n] = __builtin_amdgcn_mfma_f32_16x16x32_f16(af[m], bf[n], acc[m][n], 0, 0, 0);
      __builtin_amdgcn_s_setprio(0);
    }
  };

  stage(0, 0);
  #pragma unroll 1
  for (int t = 0; t < 16; ++t) {
    VMCNT(0);                              // own loads for tile t retired to LDS
    __builtin_amdgcn_s_barrier();          // all waves: tile t visible; t-1 reads done
    __builtin_amdgcn_sched_barrier(0);
    if (t < 15) stage((t + 1) & 1, t + 1); // 8 loads fly under compute(t)
    __builtin_amdgcn_sched_barrier(0);
    compute(t & 1);
  }

  // epilogue: rowwise dot with shifted h (f16->f32), reduce over 16 lanes
  #pragma unroll
  for (int m = 0; m < 4; ++m) {
    #pragma unroll
    for (int reg = 0; reg < 4; ++reg) {
      const int rl = wr * 64 + m * 16 + fgrp * 4 + reg;
      const int gr = r0 + rl;
      float sum = 0.f;
      if (((gr + 1) & (S - 1)) != 0) {
        const u16* hrow = Hf + (size_t)(gr + 1) * D + n0g + wc * 64 + frow;
        #pragma unroll
        for (int n = 0; n < 4; ++n)
          sum = fmaf(acc[m][n][reg], h2f(hrow[n * 16]), sum);
      }
      #pragma unroll
      for (int off = 1; off < 16; off <<= 1) sum += __shfl_xor(sum, off, 64);
      if (frow == 0) adjp[wc][rl] = sum;
    }
  }
  __syncthreads();
  if (tid < 128) {
    adj_part[(size_t)nt * BS + r0 + tid] = adjp[0][tid] + adjp[1][tid];
  }
}

// ---------------------------------------------------------------- score_flag
__global__ void score_flag(const float* __restrict__ adj_part,
                           const float* __restrict__ sig_temp, const float* __restrict__ sig_thr,
                           const float* __restrict__ noise_u,
                           unsigned char* __restrict__ hard, int* __restrict__ flags,
                           int* __restrict__ fcnt) {
  const int idx = blockIdx.x * 256 + threadIdx.x;
  const int s = idx & (S - 1);
  float sc = 0.f;
  if (s > 0) {
    float a = 0.f;
    #pragma unroll
    for (int p = 0; p < 8; ++p) a += adj_part[(size_t)p * BS + idx - 1];
    sc = a * SCALE;
  }
  const float temp = sig_temp[0], thr = sig_thr[0];
  float pr = 1.f / (1.f + expf(-(sc - thr) / temp));
  pr = fminf(fmaxf(pr, 0.f), 1.f);
  if (s == 0) pr = 1.f;
  const float p = fminf(fmaxf(pr, FEPS), 1.f - FEPS);
  const float lgt = logf(p) - log1pf(-p);
  const float uu = fminf(fmaxf(noise_u[idx], FEPS), 1.f - FEPS);
  const float lgs = logf(uu) - log1pf(-uu);
  const float z = lgt + lgs;
  hard[idx] = (z > 0.f) ? 1 : 0;
  if (s > 0 && fabsf(z) < 1e-3f) {
    const int k = atomicAdd(fcnt, 1);
    if (k < MAXF) flags[k] = idx;
  }
}

// ---------------------------------------------------------------- fixup_part
__global__ __launch_bounds__(256) void fixup_part(const int* __restrict__ flags,
    const int* __restrict__ fcnt, const float* __restrict__ hidden,
    const float* __restrict__ pos, const float* __restrict__ Gf32,
    float* __restrict__ pz) {
  __shared__ float h0s[1024];
  __shared__ float h1s[1024];
  __shared__ float red[4];
  const int t = threadIdx.x;
  const int slice = blockIdx.x & 7;
  const int nf = min(*fcnt, MAXF);
  for (int w = blockIdx.x >> 3; w < nf; w += 32) {
    const int idx = flags[w];
    #pragma unroll
    for (int rr = 0; rr < 2; ++rr) {
      const int r = idx - 1 + rr;
      float* hs = rr ? h1s : h0s;
      const float4 hv = ((const float4*)(hidden + (size_t)r * D))[t];
      const float4 pv = ((const float4*)(pos + (size_t)(r & (S - 1)) * D))[t];
      const float x0 = hv.x + pv.x, x1 = hv.y + pv.y, x2 = hv.z + pv.z, x3 = hv.w + pv.w;
      float ss = x0 * x0 + x1 * x1 + x2 * x2 + x3 * x3;
      #pragma unroll
      for (int m = 1; m < 64; m <<= 1) ss += __shfl_xor(ss, m, 64);
      __syncthreads();
      if ((t & 63) == 0) red[t >> 6] = ss;
      __syncthreads();
      const float nrm = fmaxf(sqrtf(red[0] + red[1] + red[2] + red[3]), 1e-12f);
      hs[4 * t + 0] = x0 / nrm; hs[4 * t + 1] = x1 / nrm;
      hs[4 * t + 2] = x2 / nrm; hs[4 * t + 3] = x3 / nrm;
    }
    __syncthreads();
    const float4 h0v = *(const float4*)&h0s[t << 2];
    float acc = 0.f;
    const int i0 = slice << 7;
    #pragma unroll 4
    for (int i = i0; i < i0 + 128; ++i) {
      const float4 g = ((const float4*)(Gf32 + (size_t)i * D))[t];
      const float d = g.x * h0v.x + g.y * h0v.y + g.z * h0v.z + g.w * h0v.w;
      acc = fmaf(h1s[i], d, acc);
    }
    #pragma unroll
    for (int m = 1; m < 64; m <<= 1) acc += __shfl_xor(acc, m, 64);
    __syncthreads();
    if ((t & 63) == 0) red[t >> 6] = acc;
    __syncthreads();
    if (t == 0) pz[(size_t)w * 8 + slice] = red[0] + red[1] + red[2] + red[3];
    __syncthreads();
  }
}

// ---------------------------------------------------------------- decide_scan
// First: fix flagged bits for this block's batch from exact pz partials
// (absorbs fixup_final). Then: bitwise cumsum -> seg starts.
__global__ void decide_scan(unsigned char* hard_,
                            const int* __restrict__ flags, const int* __restrict__ fcnt,
                            const float* __restrict__ pz,
                            const float* __restrict__ sig_temp, const float* __restrict__ sig_thr,
                            const float* __restrict__ noise_u,
                            int* __restrict__ seg_start, int* __restrict__ nseg_out,
                            float* __restrict__ kf_out) {
  const int b = blockIdx.x, t = threadIdx.x;
  __shared__ int ssum[256];
  const int nf = min(*fcnt, MAXF);
  for (int w = t; w < nf; w += 256) {
    const int idx = flags[w];
    if ((idx >> 12) == b) {                  // idx / S == this batch
      float a = 0.f;
      #pragma unroll
      for (int p = 0; p < 8; ++p) a += pz[(size_t)w * 8 + p];
      const float sc = a * SCALE;
      const float temp = sig_temp[0], thr = sig_thr[0];
      float pr = 1.f / (1.f + expf(-(sc - thr) / temp));
      pr = fminf(fmaxf(pr, 0.f), 1.f);
      const float p = fminf(fmaxf(pr, FEPS), 1.f - FEPS);
      const float lgt = logf(p) - log1pf(-p);
      const float uu = fminf(fmaxf(noise_u[idx], FEPS), 1.f - FEPS);
      const float lgs = logf(uu) - log1pf(-uu);
      hard_[idx] = ((lgt + lgs) > 0.f) ? 1 : 0;
    }
  }
  __syncthreads();
  const uint4 hv = ((const uint4*)(hard_ + (size_t)b * S))[t];
  const uint32_t wds[4] = {hv.x, hv.y, hv.z, hv.w};
  const uint32_t bsum = hv.x + hv.y + hv.z + hv.w;
  const int loc = (int)((bsum & 255) + ((bsum >> 8) & 255) +
                        ((bsum >> 16) & 255) + (bsum >> 24));
  ssum[t] = loc;
  __syncthreads();
  for (int off = 1; off < 256; off <<= 1) {
    int v = ssum[t];
    if (t >= off) v += ssum[t - off];
    __syncthreads();
    ssum[t] = v;
    __syncthreads();
  }
  const int ktot = ssum[255];
  int cum = ssum[t] - loc;
  #pragma unroll
  for (int e = 0; e < 16; ++e) {
    const int s = (t << 4) + e;
    const int bit = (int)((wds[e >> 2] >> ((e & 3) * 8)) & 1);
    const int pseg = min(max(cum - 1, 0), S - 1);
    cum += bit;
    const int seg = min(max(cum - 1, 0), S - 1);
    if (s == 0 || seg != pseg) seg_start[b * S + seg] = s;
  }
  if (t == 0) {
    nseg_out[b] = min(max(ktot, 1), S);
    kf_out[b] = (float)ktot;
  }
}

// ---------------------------------------------------------------- pool_and_loss
// Wave-per-output-row pool (blocks 0..8191) + loss in block 8192.
__global__ void pool_and_loss(const u16* __restrict__ Hf,
                              const int* __restrict__ seg_start,
                              const int* __restrict__ nseg_arr,
                              const float* __restrict__ kf,
                              float* __restrict__ out) {
  if (blockIdx.x == BS / 4) {
    const int t = threadIdx.x;
    if (t >= 64) return;
    float lp = 0.f;
    if (t < 8) {
      const float n = 4096.f;
      const float k = kf[t];
      lp = lgammaf(n + 1.f) - lgammaf(k + 1.f) - lgammaf(n - k + 1.f)
         + k * logf(0.2f) + (n - k) * log1pf(-0.2f);
    }
    #pragma unroll
    for (int off = 1; off < 8; off <<= 1) lp += __shfl_xor(lp, off, 64);
    if (t == 0) out[(size_t)BS * 1024] = -(lp / 8.f) / 4096.f;
    return;
  }
  const int gw = (blockIdx.x << 2) + (threadIdx.x >> 6);  // 0..32767
  const int j = gw >> 3, b = gw & 7;
  const int lane = threadIdx.x & 63;
  const int ns = nseg_arr[b];
  float4* o = (float4*)(out + (((size_t)j * Bb + b) << 10));
  if (j >= ns) {
    #pragma unroll
    for (int i = 0; i < 4; ++i) o[lane + (i << 6)] = (float4){0.f, 0.f, 0.f, 0.f};
    return;
  }
  const int s0 = seg_start[b * S + j];
  const int s1 = (j + 1 < ns) ? seg_start[b * S + j + 1] : S;
  float4 a[4];
  #pragma unroll
  for (int i = 0; i < 4; ++i) a[i] = (float4){0.f, 0.f, 0.f, 0.f};
  for (int s = s0; s < s1; ++s) {
    const ushort4* hrow = (const ushort4*)(Hf + (((size_t)b * S + s) << 10));
    #pragma unroll
    for (int i = 0; i < 4; ++i) {
      const ushort4 hv = hrow[lane + (i << 6)];
      a[i].x += h2f(hv.x); a[i].y += h2f(hv.y);
      a[i].z += h2f(hv.z); a[i].w += h2f(hv.w);
    }
  }
  const float inv = 1.f / (float)(s1 - s0);
  #pragma unroll
  for (int i = 0; i < 4; ++i)
    o[lane + (i << 6)] = (float4){a[i].x * inv, a[i].y * inv, a[i].z * inv, a[i].w * inv};
}

}  // namespace

extern "C" void kernel_launch(void* const* d_in, const int* in_sizes, int n_in,
                              void* d_out, int out_size, void* d_ws, size_t ws_size,
                              hipStream_t stream) {
  (void)in_sizes; (void)n_in; (void)out_size; (void)ws_size;
  const float* hidden = (const float*)d_in[0];
  const float* pos    = (const float*)d_in[1];
  const float* Wq     = (const float*)d_in[2];
  const float* Wk     = (const float*)d_in[3];
  const float* stemp  = (const float*)d_in[4];
  const float* sthr   = (const float*)d_in[5];
  const float* nois   = (const float*)d_in[6];
  float* out = (float*)d_out;
  char* ws = (char*)d_ws;

  // workspace layout (bytes)
  u16*   Hf        = (u16*)(ws);                       // 67,108,864 (f16 bits)
  u16*   Gf16      = (u16*)(ws + 67108864);            //  2,097,152
  float* Gf32      = (float*)(ws + 69206016);          //  4,194,304
  float* adj_part  = (float*)(ws + 73400320);          //  1,048,576 (8 x BS f32)
  unsigned char* hard = (unsigned char*)(ws + 74448896); //   32,768
  int*   flags     = (int*)(ws + 74481664);            //     16,384 (MAXF ints)
  float* pz        = (float*)(ws + 74498048);          //    131,072 (MAXF x 8 f32)
  int*   fcnt      = (int*)(ws + 74629120);            //         64
  int*   seg_start = (int*)(ws + 74629184);            //    131,072
  int*   nseg      = (int*)(ws + 74760256);            //         64
  float* kf        = (float*)(ws + 74760320);          //         64
  float* Gpart     = (float*)(ws + 74760384);          // 33,554,432 (8 x 1024^2 f32)

  hipLaunchKernelGGL(prep_and_gpart, dim3(NGP + BS/4), dim3(256), 0, stream,
                     hidden, pos, Hf, fcnt, Wq, Wk, Gpart);
  hipLaunchKernelGGL(gemm_G_comb,  dim3(1024),      dim3(256), 0, stream, Gpart, Gf32, Gf16);
  hipLaunchKernelGGL(gemm_main,    dim3(2048),      dim3(256), 0, stream, Hf, Gf16, adj_part);
  hipLaunchKernelGGL(score_flag,   dim3(BS/256),    dim3(256), 0, stream, adj_part, stemp, sthr, nois, hard, flags, fcnt);
  hipLaunchKernelGGL(fixup_part,   dim3(256),       dim3(256), 0, stream, flags, fcnt, hidden, pos, Gf32, pz);
  hipLaunchKernelGGL(decide_scan,  dim3(Bb),        dim3(256), 0, stream, hard, flags, fcnt, pz, stemp, sthr, nois, seg_start, nseg, kf);
  hipLaunchKernelGGL(pool_and_loss, dim3(BS/4 + 1), dim3(256), 0, stream, Hf, seg_start, nseg, kf, out);
}

// Round 16
// 223.115 us; speedup vs baseline: 1.0116x; 1.0116x over previous
//
#include <hip/hip_runtime.h>
#include <stdint.h>

namespace {

constexpr int Bb = 8, S = 4096, D = 1024, BS = 32768;
constexpr float SCALE = 0.08838834764831845f;           // (D/NUM_HEADS)^-0.5
constexpr float FEPS  = 1.1920928955078125e-07f;        // float32 eps (2^-23)
constexpr int MAXF = 4096;                              // max rescued items
constexpr int NGP = 512;                                // gemm_G_part blocks

typedef unsigned short u16;
typedef __attribute__((ext_vector_type(8))) _Float16 f16x8;
typedef __attribute__((ext_vector_type(4))) float    f32x4;

__device__ __forceinline__ u16 f2h(float f) {
  _Float16 h = (_Float16)f;
  return __builtin_bit_cast(u16, h);
}
__device__ __forceinline__ float h2f(u16 u) {
  return (float)__builtin_bit_cast(_Float16, u);
}
__device__ __forceinline__ void gload_lds16(const void* g, void* l) {
  __builtin_amdgcn_global_load_lds((const __attribute__((address_space(1))) void*)g,
                                   (__attribute__((address_space(3))) void*)l, 16, 0, 0);
}
#define VMCNT(n) asm volatile("s_waitcnt vmcnt(" #n ")" ::: "memory")

// ---------------------------------------------------------------- prep_and_gpart
// Fused launch: blocks [0,NGP) run the K-split G partial GEMM (compute-bound),
// blocks [NGP, NGP+8192) run prep_h (HBM-bound); G GEMM overlaps under prep's
// 208 MB stream.
__global__ __launch_bounds__(256) void prep_and_gpart(
    const float* __restrict__ hidden, const float* __restrict__ pos,
    u16* __restrict__ Hf, int* __restrict__ fcnt,
    const float* __restrict__ Wq, const float* __restrict__ Wk,
    float* __restrict__ Gpart) {
  __shared__ float Qs[32][132];
  __shared__ float Ks[32][132];
  const int bid = blockIdx.x;
  const int t = threadIdx.x;

  if (bid < NGP) {
    // ---- gemm_G_part branch: 128x128 tile, 8x8/thread, K-slice of 128.
    const int i0 = (bid & 7) * 128, j0 = ((bid >> 3) & 7) * 128;
    const int kz = (bid >> 6) * 128;
    const int tx = t & 15, ty = t >> 4;
    float acc[8][8] = {};
    for (int k0 = kz; k0 < kz + 128; k0 += 32) {
      #pragma unroll
      for (int q = 0; q < 4; ++q) {
        const int c = t + q * 256;
        const int row = c >> 5, c4 = (c & 31) << 2;
        *(float4*)&Qs[row][c4] = *(const float4*)&Wq[(size_t)(k0 + row) * D + i0 + c4];
        *(float4*)&Ks[row][c4] = *(const float4*)&Wk[(size_t)(k0 + row) * D + j0 + c4];
      }
      __syncthreads();
      #pragma unroll 4
      for (int kk = 0; kk < 32; ++kk) {
        float qv[8], kv[8];
        *(float4*)&qv[0] = *(const float4*)&Qs[kk][ty << 3];
        *(float4*)&qv[4] = *(const float4*)&Qs[kk][(ty << 3) + 4];
        *(float4*)&kv[0] = *(const float4*)&Ks[kk][tx << 3];
        *(float4*)&kv[4] = *(const float4*)&Ks[kk][(tx << 3) + 4];
        #pragma unroll
        for (int a = 0; a < 8; ++a)
          #pragma unroll
          for (int b = 0; b < 8; ++b) acc[a][b] = fmaf(qv[a], kv[b], acc[a][b]);
      }
      __syncthreads();
    }
    float* gp = Gpart + (size_t)(bid >> 6) * 1048576;
    #pragma unroll
    for (int a = 0; a < 8; ++a) {
      const size_t base = (size_t)(i0 + (ty << 3) + a) * D + j0 + (tx << 3);
      *(float4*)&gp[base]     = make_float4(acc[a][0], acc[a][1], acc[a][2], acc[a][3]);
      *(float4*)&gp[base + 4] = make_float4(acc[a][4], acc[a][5], acc[a][6], acc[a][7]);
    }
    return;
  }

  // ---- prep_h branch: wave-per-row, shuffle-only reduce.
  const int pb = bid - NGP;
  if (pb == 0 && t == 0) *fcnt = 0;
  const int r = (pb << 2) + (t >> 6);                   // row in [0, BS)
  const int lane = t & 63;
  const float4* hrow = (const float4*)(hidden + (size_t)r * D);
  const float4* prow = (const float4*)(pos + (size_t)(r & (S - 1)) * D);
  float4 x[4];
  float ss = 0.f;
  #pragma unroll
  for (int i = 0; i < 4; ++i) {
    const int c = lane + (i << 6);
    const float4 hv = hrow[c];
    const float4 pv = prow[c];
    x[i].x = hv.x + pv.x; x[i].y = hv.y + pv.y;
    x[i].z = hv.z + pv.z; x[i].w = hv.w + pv.w;
    ss += x[i].x * x[i].x + x[i].y * x[i].y + x[i].z * x[i].z + x[i].w * x[i].w;
  }
  #pragma unroll
  for (int m = 1; m < 64; m <<= 1) ss += __shfl_xor(ss, m, 64);
  const float inv = 1.f / fmaxf(sqrtf(ss), 1e-12f);
  ushort4* orow = (ushort4*)(Hf + (size_t)r * D);
  #pragma unroll
  for (int i = 0; i < 4; ++i) {
    const int c = lane + (i << 6);
    orow[c] = make_ushort4(f2h(x[i].x * inv), f2h(x[i].y * inv),
                           f2h(x[i].z * inv), f2h(x[i].w * inv));
  }
}

// ---------------------------------------------------------------- gemm_G_comb
// Fixed-order sum of 8 K-slice partials -> Gf32 + Gf16.
__global__ void gemm_G_comb(const float* __restrict__ Gpart,
                            float* __restrict__ Gf32, u16* __restrict__ Gf16) {
  const size_t e = ((size_t)blockIdx.x * 256 + threadIdx.x) * 4;
  float4 a = *(const float4*)&Gpart[e];
  #pragma unroll
  for (int z = 1; z < 8; ++z) {
    const float4 p = *(const float4*)&Gpart[(size_t)z * 1048576 + e];
    a.x += p.x; a.y += p.y; a.z += p.z; a.w += p.w;
  }
  *(float4*)&Gf32[e] = a;
  *(ushort4*)&Gf16[e] = make_ushort4(f2h(a.x), f2h(a.y), f2h(a.z), f2h(a.w));
}

// ---------------------------------------------------------------- gemm_main
// fp16 MFMA GEMM, 128x128 tile, BK=32 double-buffer: LDS = 2x8KB x2 = 32KB
// -> 3 blocks/CU (m97-class occupancy; R11's BK=64 dbuf was 66KB -> only 2).
// Same proven stage-early schedule: vmcnt(0); barrier; SB; stage(t+1); SB;
// compute(t). 64B-row swizzle (rule 21, both sides): store (row,s) <- global
// chunk s^sw(row), sw(row)=(row>>1)&3; read chunk fgrp at slot fgrp^sw ->
// per-lane constant cb. Lanes 0-15 hit 8 distinct 16B slots per 8 rows ->
// 2-way conflict = free. Grid 2048 = 256 mt x 8 nt, XCD-swizzled.
// Fused epilogue: adj_part[nt][r] = sum_{i in tile} U[r,i]*Hf[r+1,i].
__global__ __launch_bounds__(256, 2) void gemm_main(
    const u16* __restrict__ Hf, const u16* __restrict__ Gf,
    float* __restrict__ adj_part) {
  __shared__ u16 Abuf[2][4096];       // 2 x 8KB (128 rows x 32 k)
  __shared__ u16 Bbuf[2][4096];       // 2 x 8KB (128 rows x 32 k)
  __shared__ float adjp[2][128];

  const int tid = threadIdx.x;
  const int bid = blockIdx.x;
  const int swz = (bid & 7) * 256 + (bid >> 3);  // XCD swizzle
  const int mt = swz >> 3, nt = swz & 7;
  const int r0 = mt << 7;             // 128-row block
  const int n0g = nt << 7;            // 128-col block

  const int wave = tid >> 6, lane = tid & 63;
  const int wr = wave >> 1;           // 0..1 -> rows wr*64
  const int wc = wave & 1;            // 0..1 -> cols wc*64
  const int frow = lane & 15;
  const int fgrp = lane >> 4;         // 0..3 (16B k-chunk)
  const int cb = (fgrp ^ ((frow >> 1) & 3)) << 4;   // swizzled frag byte col
  const int Abase = (wr * 64 + frow) * 64;          // bytes (64B rows)
  const int Bbase = (wc * 64 + frow) * 64;          // bytes

  // staging: thread covers 16B at LDS byte tid*16 within each 64-row chunk;
  // row = q*64 + (tid>>2), slot = tid&3; source chunk = slot ^ sw(row),
  // sw(row) = (row>>1)&3 = (tid>>3)&3 (q*32 == 0 mod 4).
  const int srow = tid >> 2;                        // 0..63
  const int sslot = (tid & 3) ^ ((tid >> 3) & 3);   // pre-swizzled src slot
  const char* Asrc = (const char*)Hf + (size_t)(r0 + srow) * 2048 + sslot * 16;
  const char* Bsrc = (const char*)Gf + (size_t)(n0g + srow) * 2048 + sslot * 16;
  const int dst16 = tid * 16;

  f32x4 acc[4][4];
  #pragma unroll
  for (int m = 0; m < 4; ++m)
    #pragma unroll
    for (int n = 0; n < 4; ++n) acc[m][n] = (f32x4){0.f, 0.f, 0.f, 0.f};

  // stage tile kt: A (128x32 f16 = 8KB) + B (8KB); 4 gload_lds per thread.
  auto stage = [&](int b, int kt) {
    #pragma unroll
    for (int q = 0; q < 2; ++q) {
      gload_lds16(Asrc + (size_t)q * 131072 + (size_t)kt * 64,
                  (char*)&Abuf[b][0] + q * 4096 + dst16);
      gload_lds16(Bsrc + (size_t)q * 131072 + (size_t)kt * 64,
                  (char*)&Bbuf[b][0] + q * 4096 + dst16);
    }
  };

  auto compute = [&](int b) {
    const char* Ab = (const char*)&Abuf[b][0];
    const char* Bp = (const char*)&Bbuf[b][0];
    f16x8 bf[4], af[4];
    #pragma unroll
    for (int n = 0; n < 4; ++n) bf[n] = *(const f16x8*)(Bp + Bbase + n * 1024 + cb);
    #pragma unroll
    for (int m = 0; m < 4; ++m) af[m] = *(const f16x8*)(Ab + Abase + m * 1024 + cb);
    __builtin_amdgcn_s_setprio(1);
    #pragma unroll
    for (int m = 0; m < 4; ++m)
      #pragma unroll
      for (int n = 0; n < 4; ++n)
        acc[m][n] = __builtin_amdgcn_mfma_f32_16x16x32_f16(af[m], bf[n], acc[m][n], 0, 0, 0);
    __builtin_amdgcn_s_setprio(0);
  };

  stage(0, 0);
  #pragma unroll 1
  for (int t = 0; t < 32; ++t) {
    VMCNT(0);                              // own loads for tile t retired to LDS
    __builtin_amdgcn_s_barrier();          // all waves: tile t visible; t-1 reads done
    __builtin_amdgcn_sched_barrier(0);
    if (t < 31) stage((t + 1) & 1, t + 1); // 4 loads fly under compute(t)
    __builtin_amdgcn_sched_barrier(0);
    compute(t & 1);
  }

  // epilogue: rowwise dot with shifted h (f16->f32), reduce over 16 lanes
  #pragma unroll
  for (int m = 0; m < 4; ++m) {
    #pragma unroll
    for (int reg = 0; reg < 4; ++reg) {
      const int rl = wr * 64 + m * 16 + fgrp * 4 + reg;
      const int gr = r0 + rl;
      float sum = 0.f;
      if (((gr + 1) & (S - 1)) != 0) {
        const u16* hrow = Hf + (size_t)(gr + 1) * D + n0g + wc * 64 + frow;
        #pragma unroll
        for (int n = 0; n < 4; ++n)
          sum = fmaf(acc[m][n][reg], h2f(hrow[n * 16]), sum);
      }
      #pragma unroll
      for (int off = 1; off < 16; off <<= 1) sum += __shfl_xor(sum, off, 64);
      if (frow == 0) adjp[wc][rl] = sum;
    }
  }
  __syncthreads();
  if (tid < 128) {
    adj_part[(size_t)nt * BS + r0 + tid] = adjp[0][tid] + adjp[1][tid];
  }
}

// ---------------------------------------------------------------- score_flag
__global__ void score_flag(const float* __restrict__ adj_part,
                           const float* __restrict__ sig_temp, const float* __restrict__ sig_thr,
                           const float* __restrict__ noise_u,
                           unsigned char* __restrict__ hard, int* __restrict__ flags,
                           int* __restrict__ fcnt) {
  const int idx = blockIdx.x * 256 + threadIdx.x;
  const int s = idx & (S - 1);
  float sc = 0.f;
  if (s > 0) {
    float a = 0.f;
    #pragma unroll
    for (int p = 0; p < 8; ++p) a += adj_part[(size_t)p * BS + idx - 1];
    sc = a * SCALE;
  }
  const float temp = sig_temp[0], thr = sig_thr[0];
  float pr = 1.f / (1.f + expf(-(sc - thr) / temp));
  pr = fminf(fmaxf(pr, 0.f), 1.f);
  if (s == 0) pr = 1.f;
  const float p = fminf(fmaxf(pr, FEPS), 1.f - FEPS);
  const float lgt = logf(p) - log1pf(-p);
  const float uu = fminf(fmaxf(noise_u[idx], FEPS), 1.f - FEPS);
  const float lgs = logf(uu) - log1pf(-uu);
  const float z = lgt + lgs;
  hard[idx] = (z > 0.f) ? 1 : 0;
  if (s > 0 && fabsf(z) < 1e-3f) {
    const int k = atomicAdd(fcnt, 1);
    if (k < MAXF) flags[k] = idx;
  }
}

// ---------------------------------------------------------------- fixup_part
__global__ __launch_bounds__(256) void fixup_part(const int* __restrict__ flags,
    const int* __restrict__ fcnt, const float* __restrict__ hidden,
    const float* __restrict__ pos, const float* __restrict__ Gf32,
    float* __restrict__ pz) {
  __shared__ float h0s[1024];
  __shared__ float h1s[1024];
  __shared__ float red[4];
  const int t = threadIdx.x;
  const int slice = blockIdx.x & 7;
  const int nf = min(*fcnt, MAXF);
  for (int w = blockIdx.x >> 3; w < nf; w += 32) {
    const int idx = flags[w];
    #pragma unroll
    for (int rr = 0; rr < 2; ++rr) {
      const int r = idx - 1 + rr;
      float* hs = rr ? h1s : h0s;
      const float4 hv = ((const float4*)(hidden + (size_t)r * D))[t];
      const float4 pv = ((const float4*)(pos + (size_t)(r & (S - 1)) * D))[t];
      const float x0 = hv.x + pv.x, x1 = hv.y + pv.y, x2 = hv.z + pv.z, x3 = hv.w + pv.w;
      float ss = x0 * x0 + x1 * x1 + x2 * x2 + x3 * x3;
      #pragma unroll
      for (int m = 1; m < 64; m <<= 1) ss += __shfl_xor(ss, m, 64);
      __syncthreads();
      if ((t & 63) == 0) red[t >> 6] = ss;
      __syncthreads();
      const float nrm = fmaxf(sqrtf(red[0] + red[1] + red[2] + red[3]), 1e-12f);
      hs[4 * t + 0] = x0 / nrm; hs[4 * t + 1] = x1 / nrm;
      hs[4 * t + 2] = x2 / nrm; hs[4 * t + 3] = x3 / nrm;
    }
    __syncthreads();
    const float4 h0v = *(const float4*)&h0s[t << 2];
    float acc = 0.f;
    const int i0 = slice << 7;
    #pragma unroll 4
    for (int i = i0; i < i0 + 128; ++i) {
      const float4 g = ((const float4*)(Gf32 + (size_t)i * D))[t];
      const float d = g.x * h0v.x + g.y * h0v.y + g.z * h0v.z + g.w * h0v.w;
      acc = fmaf(h1s[i], d, acc);
    }
    #pragma unroll
    for (int m = 1; m < 64; m <<= 1) acc += __shfl_xor(acc, m, 64);
    __syncthreads();
    if ((t & 63) == 0) red[t >> 6] = acc;
    __syncthreads();
    if (t == 0) pz[(size_t)w * 8 + slice] = red[0] + red[1] + red[2] + red[3];
    __syncthreads();
  }
}

// ---------------------------------------------------------------- decide_scan
// First: fix flagged bits for this block's batch from exact pz partials
// (absorbs fixup_final). Then: bitwise cumsum -> seg starts.
__global__ void decide_scan(unsigned char* hard_,
                            const int* __restrict__ flags, const int* __restrict__ fcnt,
                            const float* __restrict__ pz,
                            const float* __restrict__ sig_temp, const float* __restrict__ sig_thr,
                            const float* __restrict__ noise_u,
                            int* __restrict__ seg_start, int* __restrict__ nseg_out,
                            float* __restrict__ kf_out) {
  const int b = blockIdx.x, t = threadIdx.x;
  __shared__ int ssum[256];
  const int nf = min(*fcnt, MAXF);
  for (int w = t; w < nf; w += 256) {
    const int idx = flags[w];
    if ((idx >> 12) == b) {                  // idx / S == this batch
      float a = 0.f;
      #pragma unroll
      for (int p = 0; p < 8; ++p) a += pz[(size_t)w * 8 + p];
      const float sc = a * SCALE;
      const float temp = sig_temp[0], thr = sig_thr[0];
      float pr = 1.f / (1.f + expf(-(sc - thr) / temp));
      pr = fminf(fmaxf(pr, 0.f), 1.f);
      const float p = fminf(fmaxf(pr, FEPS), 1.f - FEPS);
      const float lgt = logf(p) - log1pf(-p);
      const float uu = fminf(fmaxf(noise_u[idx], FEPS), 1.f - FEPS);
      const float lgs = logf(uu) - log1pf(-uu);
      hard_[idx] = ((lgt + lgs) > 0.f) ? 1 : 0;
    }
  }
  __syncthreads();
  const uint4 hv = ((const uint4*)(hard_ + (size_t)b * S))[t];
  const uint32_t wds[4] = {hv.x, hv.y, hv.z, hv.w};
  const uint32_t bsum = hv.x + hv.y + hv.z + hv.w;
  const int loc = (int)((bsum & 255) + ((bsum >> 8) & 255) +
                        ((bsum >> 16) & 255) + (bsum >> 24));
  ssum[t] = loc;
  __syncthreads();
  for (int off = 1; off < 256; off <<= 1) {
    int v = ssum[t];
    if (t >= off) v += ssum[t - off];
    __syncthreads();
    ssum[t] = v;
    __syncthreads();
  }
  const int ktot = ssum[255];
  int cum = ssum[t] - loc;
  #pragma unroll
  for (int e = 0; e < 16; ++e) {
    const int s = (t << 4) + e;
    const int bit = (int)((wds[e >> 2] >> ((e & 3) * 8)) & 1);
    const int pseg = min(max(cum - 1, 0), S - 1);
    cum += bit;
    const int seg = min(max(cum - 1, 0), S - 1);
    if (s == 0 || seg != pseg) seg_start[b * S + seg] = s;
  }
  if (t == 0) {
    nseg_out[b] = min(max(ktot, 1), S);
    kf_out[b] = (float)ktot;
  }
}

// ---------------------------------------------------------------- pool_and_loss
// Wave-per-output-row pool (blocks 0..8191) + loss in block 8192.
__global__ void pool_and_loss(const u16* __restrict__ Hf,
                              const int* __restrict__ seg_start,
                              const int* __restrict__ nseg_arr,
                              const float* __restrict__ kf,
                              float* __restrict__ out) {
  if (blockIdx.x == BS / 4) {
    const int t = threadIdx.x;
    if (t >= 64) return;
    float lp = 0.f;
    if (t < 8) {
      const float n = 4096.f;
      const float k = kf[t];
      lp = lgammaf(n + 1.f) - lgammaf(k + 1.f) - lgammaf(n - k + 1.f)
         + k * logf(0.2f) + (n - k) * log1pf(-0.2f);
    }
    #pragma unroll
    for (int off = 1; off < 8; off <<= 1) lp += __shfl_xor(lp, off, 64);
    if (t == 0) out[(size_t)BS * 1024] = -(lp / 8.f) / 4096.f;
    return;
  }
  const int gw = (blockIdx.x << 2) + (threadIdx.x >> 6);  // 0..32767
  const int j = gw >> 3, b = gw & 7;
  const int lane = threadIdx.x & 63;
  const int ns = nseg_arr[b];
  float4* o = (float4*)(out + (((size_t)j * Bb + b) << 10));
  if (j >= ns) {
    #pragma unroll
    for (int i = 0; i < 4; ++i) o[lane + (i << 6)] = (float4){0.f, 0.f, 0.f, 0.f};
    return;
  }
  const int s0 = seg_start[b * S + j];
  const int s1 = (j + 1 < ns) ? seg_start[b * S + j + 1] : S;
  float4 a[4];
  #pragma unroll
  for (int i = 0; i < 4; ++i) a[i] = (float4){0.f, 0.f, 0.f, 0.f};
  for (int s = s0; s < s1; ++s) {
    const ushort4* hrow = (const ushort4*)(Hf + (((size_t)b * S + s) << 10));
    #pragma unroll
    for (int i = 0; i < 4; ++i) {
      const ushort4 hv = hrow[lane + (i << 6)];
      a[i].x += h2f(hv.x); a[i].y += h2f(hv.y);
      a[i].z += h2f(hv.z); a[i].w += h2f(hv.w);
    }
  }
  const float inv = 1.f / (float)(s1 - s0);
  #pragma unroll
  for (int i = 0; i < 4; ++i)
    o[lane + (i << 6)] = (float4){a[i].x * inv, a[i].y * inv, a[i].z * inv, a[i].w * inv};
}

}  // namespace

extern "C" void kernel_launch(void* const* d_in, const int* in_sizes, int n_in,
                              void* d_out, int out_size, void* d_ws, size_t ws_size,
                              hipStream_t stream) {
  (void)in_sizes; (void)n_in; (void)out_size; (void)ws_size;
  const float* hidden = (const float*)d_in[0];
  const float* pos    = (const float*)d_in[1];
  const float* Wq     = (const float*)d_in[2];
  const float* Wk     = (const float*)d_in[3];
  const float* stemp  = (const float*)d_in[4];
  const float* sthr   = (const float*)d_in[5];
  const float* nois   = (const float*)d_in[6];
  float* out = (float*)d_out;
  char* ws = (char*)d_ws;

  // workspace layout (bytes)
  u16*   Hf        = (u16*)(ws);                       // 67,108,864 (f16 bits)
  u16*   Gf16      = (u16*)(ws + 67108864);            //  2,097,152
  float* Gf32      = (float*)(ws + 69206016);          //  4,194,304
  float* adj_part  = (float*)(ws + 73400320);          //  1,048,576 (8 x BS f32)
  unsigned char* hard = (unsigned char*)(ws + 74448896); //   32,768
  int*   flags     = (int*)(ws + 74481664);            //     16,384 (MAXF ints)
  float* pz        = (float*)(ws + 74498048);          //    131,072 (MAXF x 8 f32)
  int*   fcnt      = (int*)(ws + 74629120);            //         64
  int*   seg_start = (int*)(ws + 74629184);            //    131,072
  int*   nseg      = (int*)(ws + 74760256);            //         64
  float* kf        = (float*)(ws + 74760320);          //         64
  float* Gpart     = (float*)(ws + 74760384);          // 33,554,432 (8 x 1024^2 f32)

  hipLaunchKernelGGL(prep_and_gpart, dim3(NGP + BS/4), dim3(256), 0, stream,
                     hidden, pos, Hf, fcnt, Wq, Wk, Gpart);
  hipLaunchKernelGGL(gemm_G_comb,  dim3(1024),      dim3(256), 0, stream, Gpart, Gf32, Gf16);
  hipLaunchKernelGGL(gemm_main,    dim3(2048),      dim3(256), 0, stream, Hf, Gf16, adj_part);
  hipLaunchKernelGGL(score_flag,   dim3(BS/256),    dim3(256), 0, stream, adj_part, stemp, sthr, nois, hard, flags, fcnt);
  hipLaunchKernelGGL(fixup_part,   dim3(256),       dim3(256), 0, stream, flags, fcnt, hidden, pos, Gf32, pz);
  hipLaunchKernelGGL(decide_scan,  dim3(Bb),        dim3(256), 0, stream, hard, flags, fcnt, pz, stemp, sthr, nois, seg_start, nseg, kf);
  hipLaunchKernelGGL(pool_and_loss, dim3(BS/4 + 1), dim3(256), 0, stream, Hf, seg_start, nseg, kf, out);
}